// Round 1
// baseline (57.978 us; speedup 1.0000x reference)
//
#include <hip/hip_runtime.h>

#define P 1024
#define NB 11
#define NBINS (NB*NB*NB)   // 1331
#define BATCH 8
#define TI 8               // i-rows per block

__global__ __launch_bounds__(256) void fpfh_zero(int* __restrict__ hist) {
    int i = blockIdx.x * 256 + threadIdx.x;
    if (i < BATCH * NBINS) hist[i] = 0;
}

__global__ __launch_bounds__(256) void fpfh_main(const float* __restrict__ x,
                                                 int* __restrict__ ghist) {
    __shared__ float s[6][P];      // SoA: pos x/y/z, ori x/y/z — stride-1 LDS reads
    __shared__ int shist[NBINS];

    const int t  = threadIdx.x;
    const int b  = blockIdx.y;
    const int i0 = blockIdx.x * TI;
    const float* xb = x + b * (P * 6);

    // stage batch points into LDS (coalesced global reads)
    for (int idx = t; idx < P * 6; idx += 256) {
        float val = xb[idx];
        s[idx % 6][idx / 6] = val;
    }
    for (int k = t; k < NBINS; k += 256) shist[k] = 0;
    __syncthreads();

    const float eps = 1e-6f;

    for (int il = 0; il < TI; ++il) {
        const int i = i0 + il;
        // uniform (broadcast) LDS reads for point i
        const float pix = s[0][i], piy = s[1][i], piz = s[2][i];
        const float nix = s[3][i], niy = s[4][i], niz = s[5][i];

        for (int jt = 0; jt < P / 256; ++jt) {
            const int j = jt * 256 + t;
            const float dx = s[0][j] - pix;      // delta = pos_j - pos_i
            const float dy = s[1][j] - piy;
            const float dz = s[2][j] - piz;
            const float njx = s[3][j], njy = s[4][j], njz = s[5][j];

            const float dist = sqrtf(dx*dx + dy*dy + dz*dz);

            // v = cross(delta, ni), normalized with +eps on the norm
            float vx = dy*niz - dz*niy;
            float vy = dz*nix - dx*niz;
            float vz = dx*niy - dy*nix;
            const float vnr = 1.0f / (sqrtf(vx*vx + vy*vy + vz*vz) + eps);
            vx *= vnr; vy *= vnr; vz *= vnr;

            // w = cross(ni, v), normalized with +eps on the norm
            float wx = niy*vz - niz*vy;
            float wy = niz*vx - nix*vz;
            float wz = nix*vy - niy*vx;
            const float wnr = 1.0f / (sqrtf(wx*wx + wy*wy + wz*wz) + eps);
            wx *= wnr; wy *= wnr; wz *= wnr;

            const float alpha = vx*njx + vy*njy + vz*njz;
            const float phi   = (nix*dx + niy*dy + niz*dz) / (dist + eps);
            const float theta = atan2f(wx*njx + wy*njy + wz*njz,
                                       nix*njx + niy*njy + niz*njz)
                                / 3.14159274101257324f;   // (float)pi, matches f32 jnp.pi

            // to_idx: truncate toward zero, clamp only the top (min with 10)
            int ia  = (int)((alpha + 1.0f) * 0.5f * 11.0f); ia  = min(ia, NB - 1);
            int ip  = (int)((phi   + 1.0f) * 0.5f * 11.0f); ip  = min(ip, NB - 1);
            int ith = (int)((theta + 1.0f) * 0.5f * 11.0f); ith = min(ith, NB - 1);

            int bin = (ia * NB + ip) * NB + ith;
            // JAX scatter semantics: wrap negative once, drop anything still OOB
            if (bin < 0) bin += NBINS;
            if (j != i && bin >= 0 && bin < NBINS)
                atomicAdd(&shist[bin], 1);
        }
    }
    __syncthreads();

    int* gb = ghist + b * NBINS;
    for (int k = t; k < NBINS; k += 256) {
        int c = shist[k];
        if (c) atomicAdd(&gb[k], c);
    }
}

__global__ __launch_bounds__(256) void fpfh_convert(const int* __restrict__ hist,
                                                    float* __restrict__ out) {
    int i = blockIdx.x * 256 + threadIdx.x;
    if (i < BATCH * NBINS)
        out[i] = (float)hist[i] / 1047552.0f;   // P*(P-1) = 1024*1023
}

extern "C" void kernel_launch(void* const* d_in, const int* in_sizes, int n_in,
                              void* d_out, int out_size, void* d_ws, size_t ws_size,
                              hipStream_t stream) {
    const float* x = (const float*)d_in[0];
    float* out = (float*)d_out;
    int* hist = (int*)d_ws;          // BATCH*NBINS*4 = 42,592 B of scratch

    const int nOut = BATCH * NBINS;
    fpfh_zero<<<(nOut + 255) / 256, 256, 0, stream>>>(hist);
    dim3 grid(P / TI, BATCH);
    fpfh_main<<<grid, 256, 0, stream>>>(x, hist);
    fpfh_convert<<<(nOut + 255) / 256, 256, 0, stream>>>(hist, out);
}

// Round 2
// 38.369 us; speedup vs baseline: 1.5111x; 1.5111x over previous
//
#include <hip/hip_runtime.h>

#define P 1024
#define NB 11
#define NBINS 1331          // 11^3
#define BATCH 8
#define TI 8                // i-rows per block

// Cephes-style atan2, err ~1e-7 rad. Only needs to be accurate enough that
// bin flips (bin width = pi/5.5 = 0.57 rad) stay rare.
__device__ __forceinline__ float fast_atan2(float y, float x) {
    const float PI_F   = 3.14159274101257324f;
    const float PIO2_F = 1.57079637050628662f;
    const float PIO4_F = 0.78539818525314331f;
    float ax = __builtin_fabsf(x), ay = __builtin_fabsf(y);
    float mn = fminf(ax, ay), mx = fmaxf(ax, ay);
    float u = mn * __builtin_amdgcn_rcpf(mx);        // [0,1]
    bool  big = u > 0.4142135623730950f;             // tan(pi/8)
    float t = big ? (u - 1.0f) * __builtin_amdgcn_rcpf(u + 1.0f) : u;
    float z = t * t;
    float p = fmaf(fmaf(fmaf(8.05374449538e-2f, z, -1.38776856032e-1f), z,
                        1.99777106478e-1f), z, -3.33329491539e-1f);
    float r = fmaf(p * z, t, t);
    if (big)     r += PIO4_F;
    if (ay > ax) r = PIO2_F - r;
    if (x < 0.f) r = PI_F - r;
    return (y < 0.f) ? -r : r;
}

__global__ __launch_bounds__(256) void fpfh_zero(int* __restrict__ hist) {
    int i = blockIdx.x * 256 + threadIdx.x;
    if (i < BATCH * NBINS) hist[i] = 0;
}

__global__ __launch_bounds__(256) void fpfh_main(const float* __restrict__ x,
                                                 int* __restrict__ ghist) {
    __shared__ float4 spos[P];      // xyz + pad -> one ds_read_b128 per point
    __shared__ float4 sori[P];
    __shared__ int    shist[NBINS];

    const int t  = threadIdx.x;
    const int b  = blockIdx.y;
    const int i0 = blockIdx.x * TI;
    const float* xb = x + b * (P * 6);

    for (int idx = t; idx < P * 6; idx += 256) {
        float val = xb[idx];
        int p = idx / 6, c = idx % 6;
        if (c < 3) ((float*)&spos[p])[c]     = val;
        else       ((float*)&sori[p])[c - 3] = val;
    }
    for (int k = t; k < NBINS; k += 256) shist[k] = 0;
    __syncthreads();

    // Hoist the block's 8 i-points into registers (uniform broadcast reads).
    float4 pi_[TI], ni_[TI];
    #pragma unroll
    for (int il = 0; il < TI; ++il) {
        pi_[il] = spos[i0 + il];
        ni_[il] = sori[i0 + il];
    }

    const float eps = 1e-6f;

    #pragma unroll
    for (int jt = 0; jt < P / 256; ++jt) {
        const int j = jt * 256 + t;
        const float4 pj = spos[j];
        const float4 nj = sori[j];

        #pragma unroll
        for (int il = 0; il < TI; ++il) {
            const int i = i0 + il;
            const float nix = ni_[il].x, niy = ni_[il].y, niz = ni_[il].z;

            // delta = pos_j - pos_i
            const float dx = pj.x - pi_[il].x;
            const float dy = pj.y - pi_[il].y;
            const float dz = pj.z - pi_[il].z;
            const float dd   = fmaf(dx, dx, fmaf(dy, dy, dz * dz));
            const float dist = __builtin_amdgcn_sqrtf(dd);

            // cv = cross(delta, ni);  sv = |cv| + eps  (reference's v-norm denom)
            const float cvx = fmaf(dy, niz, -dz * niy);
            const float cvy = fmaf(dz, nix, -dx * niz);
            const float cvz = fmaf(dx, niy, -dy * nix);
            const float cvv = fmaf(cvx, cvx, fmaf(cvy, cvy, cvz * cvz));
            const float scv = __builtin_amdgcn_sqrtf(cvv);

            // alpha = v_hat . nj = (cv . nj) / (|cv| + eps)
            const float cvdnj = fmaf(cvx, nj.x, fmaf(cvy, nj.y, cvz * nj.z));
            const float alpha = cvdnj * __builtin_amdgcn_rcpf(scv + eps);

            // cw = cross(ni, cv);  w_hat = cw / (|cw| + eps*(|cv|+eps))
            const float cwx = fmaf(niy, cvz, -niz * cvy);
            const float cwy = fmaf(niz, cvx, -nix * cvz);
            const float cwz = fmaf(nix, cvy, -niy * cvx);
            const float cww = fmaf(cwx, cwx, fmaf(cwy, cwy, cwz * cwz));
            const float scw = __builtin_amdgcn_sqrtf(cww);

            const float cwdnj = fmaf(cwx, nj.x, fmaf(cwy, nj.y, cwz * nj.z));
            const float nidnj = fmaf(nix, nj.x, fmaf(niy, nj.y, niz * nj.z));
            const float nid   = fmaf(nix, dx, fmaf(niy, dy, niz * dz));

            const float phi = nid * __builtin_amdgcn_rcpf(dist + eps);

            // theta*pi = atan2(w_hat.nj, ni.nj) = atan2(cw.nj, scale*(ni.nj)), scale>0
            const float scale = fmaf(eps, scv + eps, scw);
            const float ang   = fast_atan2(cwdnj, scale * nidnj);

            // to_idx: truncate toward zero, clamp top only (theta: fold /pi into scale)
            int ia  = (int)fmaf(alpha, 5.5f, 5.5f);        ia  = min(ia, NB - 1);
            int ip  = (int)fmaf(phi,   5.5f, 5.5f);        ip  = min(ip, NB - 1);
            int ith = (int)fmaf(ang, 1.7507044f, 5.5f);    ith = min(ith, NB - 1);

            int bin = (ia * NB + ip) * NB + ith;
            if (bin < 0) bin += NBINS;               // JAX wrap-once
            if ((j != i) && ((unsigned)bin < (unsigned)NBINS))
                atomicAdd(&shist[bin], 1);           // still-OOB dropped
        }
    }
    __syncthreads();

    int* gb = ghist + b * NBINS;
    for (int k = t; k < NBINS; k += 256) {
        int c = shist[k];
        if (c) atomicAdd(&gb[k], c);
    }
}

__global__ __launch_bounds__(256) void fpfh_convert(const int* __restrict__ hist,
                                                    float* __restrict__ out) {
    int i = blockIdx.x * 256 + threadIdx.x;
    if (i < BATCH * NBINS)
        out[i] = (float)hist[i] / 1047552.0f;        // P*(P-1)
}

extern "C" void kernel_launch(void* const* d_in, const int* in_sizes, int n_in,
                              void* d_out, int out_size, void* d_ws, size_t ws_size,
                              hipStream_t stream) {
    const float* x = (const float*)d_in[0];
    float* out = (float*)d_out;
    int* hist = (int*)d_ws;          // BATCH*NBINS*4 = 42,592 B of scratch

    const int nOut = BATCH * NBINS;
    fpfh_zero<<<(nOut + 255) / 256, 256, 0, stream>>>(hist);
    dim3 grid(P / TI, BATCH);
    fpfh_main<<<grid, 256, 0, stream>>>(x, hist);
    fpfh_convert<<<(nOut + 255) / 256, 256, 0, stream>>>(hist, out);
}

// Round 3
// 30.973 us; speedup vs baseline: 1.8719x; 1.2388x over previous
//
#include <hip/hip_runtime.h>

#define P 1024
#define NB 11
#define NBINS 1331          // 11^3
#define BATCH 8
#define TI 8                // i-rows per block

// force a (block-uniform) float into an SGPR
#define RFL(f) __uint_as_float(__builtin_amdgcn_readfirstlane(__float_as_uint(f)))

__global__ __launch_bounds__(256) void fpfh_zero(int* __restrict__ hist) {
    int i = blockIdx.x * 256 + threadIdx.x;
    if (i < BATCH * NBINS) hist[i] = 0;
}

__global__ __launch_bounds__(256) void fpfh_main(const float* __restrict__ x,
                                                 int* __restrict__ ghist) {
    __shared__ int shist[NBINS];

    const int t  = threadIdx.x;
    const int b  = blockIdx.y;
    const int i0 = blockIdx.x * TI;
    const float* xb = x + b * (P * 6);

    for (int k = t; k < NBINS; k += 256) shist[k] = 0;

    // ---- hoist the block's 8 i-points into SGPRs (block-uniform values) ----
    float PIX[TI], PIY[TI], PIZ[TI], NIX[TI], NIY[TI], NIZ[TI], NII[TI], SNI[TI];
    #pragma unroll
    for (int il = 0; il < TI; ++il) {
        const float* xi = xb + (i0 + il) * 6;
        PIX[il] = RFL(xi[0]); PIY[il] = RFL(xi[1]); PIZ[il] = RFL(xi[2]);
        NIX[il] = RFL(xi[3]); NIY[il] = RFL(xi[4]); NIZ[il] = RFL(xi[5]);
        float nii = fmaf(NIX[il], NIX[il],
                    fmaf(NIY[il], NIY[il], NIZ[il] * NIZ[il]));
        NII[il] = RFL(nii);                              // |ni|^2
        SNI[il] = RFL(__builtin_amdgcn_sqrtf(nii));      // |ni|
    }

    // ---- prefetch this thread's 4 j-points (coalesced, L1/L2-resident) ----
    float pjx[4], pjy[4], pjz[4], njx[4], njy[4], njz[4];
    #pragma unroll
    for (int jt = 0; jt < 4; ++jt) {
        const float* xj = xb + (jt * 256 + t) * 6;
        pjx[jt] = xj[0]; pjy[jt] = xj[1]; pjz[jt] = xj[2];
        njx[jt] = xj[3]; njy[jt] = xj[4]; njz[jt] = xj[5];
    }

    __syncthreads();   // shist zeroed

    // theta sector boundaries at (2m-1)*pi/11: cos, sin
    const float C1 = 0.959492973614497f,  S1 = 0.281732556841430f;
    const float C2 = 0.654860733945285f,  S2 = 0.755749574354258f;
    const float C3 = 0.142314838273285f,  S3 = 0.989821441880933f;
    const float C4 = -0.415415013001886f, S4 = 0.909631995354518f;
    const float C5 = -0.841253532831181f, S5 = 0.540640817455598f;

    #pragma unroll
    for (int jt = 0; jt < 4; ++jt) {
        const int j = jt * 256 + t;

        #pragma unroll
        for (int il = 0; il < TI; ++il) {
            // delta = pos_j - pos_i
            const float dx = pjx[jt] - PIX[il];
            const float dy = pjy[jt] - PIY[il];
            const float dz = pjz[jt] - PIZ[il];

            const float dd    = fmaf(dx, dx, fmaf(dy, dy, dz * dz));
            const float nid   = fmaf(NIX[il], dx, fmaf(NIY[il], dy, NIZ[il] * dz));
            const float nidnj = fmaf(NIX[il], njx[jt],
                                fmaf(NIY[il], njy[jt], NIZ[il] * njz[jt]));
            const float ddnj  = fmaf(dx, njx[jt], fmaf(dy, njy[jt], dz * njz[jt]));

            // cv = delta x ni ;  cv . nj  (chirality term — the one real cross)
            const float cvx = fmaf(dy, NIZ[il], -dz * NIY[il]);
            const float cvy = fmaf(dz, NIX[il], -dx * NIZ[il]);
            const float cvz = fmaf(dx, NIY[il], -dy * NIX[il]);
            const float cvdnj = fmaf(cvx, njx[jt],
                                fmaf(cvy, njy[jt], cvz * njz[jt]));

            // |cv|^2 = dd*|ni|^2 - (ni.d)^2   (Lagrange; cv ⟂ ni)
            float cvv = fmaf(dd, NII[il], -nid * nid);
            cvv = fmaxf(cvv, 0.0f);
            const float rsq_cvv = __builtin_amdgcn_rsqf(cvv);
            const float alpha = cvdnj * rsq_cvv;
            const float scv   = cvv * rsq_cvv;           // |cv|

            const float phi = nid * __builtin_amdgcn_rsqf(dd);

            // theta = atan2(cw.nj, |cw| * (ni.nj)),  cw = ni x cv
            // cw.nj = |ni|^2 (d.nj) - (ni.d)(ni.nj);  |cw| = |ni| |cv|
            const float y_t = fmaf(NII[il], ddnj, -nid * nidnj);
            const float x_t = (SNI[il] * nidnj) * scv;
            const float ay  = __builtin_fabsf(y_t);

            // bin(theta) via 5 sign tests against boundaries (2m-1)pi/11
            int k = (fmaf(ay, C1, -x_t * S1) > 0.0f)
                  + (fmaf(ay, C2, -x_t * S2) > 0.0f)
                  + (fmaf(ay, C3, -x_t * S3) > 0.0f)
                  + (fmaf(ay, C4, -x_t * S4) > 0.0f)
                  + (fmaf(ay, C5, -x_t * S5) > 0.0f);
            const int ith = (y_t < 0.0f) ? 5 - k : 5 + k;   // in [0,10]

            int ia = (int)fmaf(alpha, 5.5f, 5.5f); ia = min(ia, NB - 1);
            int ip = (int)fmaf(phi,   5.5f, 5.5f); ip = min(ip, NB - 1);

            int bin = (ia * NB + ip) * NB + ith;
            if (bin < 0) bin += NBINS;               // JAX wrap-once
            if ((j != i0 + il) && ((unsigned)bin < (unsigned)NBINS))
                atomicAdd(&shist[bin], 1);           // still-OOB dropped
        }
    }
    __syncthreads();

    int* gb = ghist + b * NBINS;
    for (int k = t; k < NBINS; k += 256) {
        int c = shist[k];
        if (c) atomicAdd(&gb[k], c);
    }
}

__global__ __launch_bounds__(256) void fpfh_convert(const int* __restrict__ hist,
                                                    float* __restrict__ out) {
    int i = blockIdx.x * 256 + threadIdx.x;
    if (i < BATCH * NBINS)
        out[i] = (float)hist[i] / 1047552.0f;        // P*(P-1)
}

extern "C" void kernel_launch(void* const* d_in, const int* in_sizes, int n_in,
                              void* d_out, int out_size, void* d_ws, size_t ws_size,
                              hipStream_t stream) {
    const float* x = (const float*)d_in[0];
    float* out = (float*)d_out;
    int* hist = (int*)d_ws;          // BATCH*NBINS*4 = 42,592 B of scratch

    const int nOut = BATCH * NBINS;
    fpfh_zero<<<(nOut + 255) / 256, 256, 0, stream>>>(hist);
    dim3 grid(P / TI, BATCH);
    fpfh_main<<<grid, 256, 0, stream>>>(x, hist);
    fpfh_convert<<<(nOut + 255) / 256, 256, 0, stream>>>(hist, out);
}